// Round 1
// baseline (382.868 us; speedup 1.0000x reference)
//
#include <hip/hip_runtime.h>

// 2D db2 LL band: out[jh,jw] = sum_{a,b} g[a]*g[b]*x[symH(2jh-2+a), symW(2jw-2+b)]
// g = DEC_LO reversed. H=W=512 -> OH=OW=257. N*C = 256 planes.

#define IN_H 512
#define IN_W 512
#define OUT_H 257
#define OUT_W 257

// Output tile per block
#define TW 64
#define TH 16
// Input patch needed: 2*T + 2
#define IW_T (2 * TW + 2)   // 130
#define IH_T (2 * TH + 2)   // 34
#define LDS_STRIDE (IW_T + 2) // 132, keeps float2 alignment (even)

__global__ __launch_bounds__(256, 2)
void dwt_ll_kernel(const float* __restrict__ x, float* __restrict__ out) {
    __shared__ float tile[IH_T][LDS_STRIDE];

    const int tid = threadIdx.x;
    const int jw0 = blockIdx.x * TW;
    const int jh0 = blockIdx.y * TH;
    const int plane = blockIdx.z;

    const float* __restrict__ xp = x + (size_t)plane * (IN_H * IN_W);
    float* __restrict__ op = out + (size_t)plane * (OUT_H * OUT_W);

    const int rbase = 2 * jh0 - 2;
    const int cbase = 2 * jw0 - 2;

    // ---- Stage input patch (with symmetric boundary remap) into LDS ----
    for (int idx = tid; idx < IH_T * IW_T; idx += 256) {
        int r = idx / IW_T;
        int c = idx - r * IW_T;
        int gr = rbase + r;
        int gc = cbase + c;
        gr = (gr < 0) ? (-gr - 1) : gr;
        gr = (gr >= IN_H) ? (2 * IN_H - 1 - gr) : gr;
        gc = (gc < 0) ? (-gc - 1) : gc;
        gc = (gc >= IN_W) ? (2 * IN_W - 1 - gc) : gc;
        tile[r][c] = xp[gr * IN_W + gc];
    }
    __syncthreads();

    // db2 dec_lo reversed
    const float g0 = 0.48296291314469025f;
    const float g1 = 0.8365163037378079f;
    const float g2 = 0.22414386804185735f;
    const float g3 = -0.12940952255092145f;

    const int tx = tid & 63;   // output col within tile
    const int ty = tid >> 6;   // 0..3, handles 4 output rows each
    const int ow = jw0 + tx;
    if (ow >= OUT_W) return;   // no later barriers, safe

    const int cc = 2 * tx;     // LDS col base (even -> 8B aligned)
    const int r0 = 8 * ty;     // LDS row base for this thread's 10 rows

    // Horizontal low-pass on the 10 input rows this thread's 4 outputs need
    float h[10];
#pragma unroll
    for (int r = 0; r < 10; ++r) {
        const float2 a = *(const float2*)&tile[r0 + r][cc];
        const float2 b = *(const float2*)&tile[r0 + r][cc + 2];
        h[r] = g0 * a.x + g1 * a.y + g2 * b.x + g3 * b.y;
    }

    // Vertical low-pass -> 4 outputs
#pragma unroll
    for (int k = 0; k < 4; ++k) {
        const int oh = jh0 + ty * 4 + k;
        if (oh < OUT_H) {
            const float v = g0 * h[2 * k] + g1 * h[2 * k + 1]
                          + g2 * h[2 * k + 2] + g3 * h[2 * k + 3];
            op[oh * OUT_W + ow] = v;
        }
    }
}

extern "C" void kernel_launch(void* const* d_in, const int* in_sizes, int n_in,
                              void* d_out, int out_size, void* d_ws, size_t ws_size,
                              hipStream_t stream) {
    const float* x = (const float*)d_in[0];
    float* out = (float*)d_out;

    // (4,64,512,512) -> planes = 256; output tiles: ceil(257/64)=5, ceil(257/16)=17
    dim3 grid((OUT_W + TW - 1) / TW, (OUT_H + TH - 1) / TH, 4 * 64);
    dim3 block(256);
    dwt_ll_kernel<<<grid, block, 0, stream>>>(x, out);
}